// Round 5
// baseline (894.812 us; speedup 1.0000x reference)
//
#include <hip/hip_runtime.h>
#include <math.h>

#define N_CFG 400000
#define E_CFG 1600000
#define N_FUNC 8000
#define N_EXT 1600
#define N_FCG (N_FUNC + N_EXT)
#define E_FCG 80000
#define NBATCH 8
#define VOCAB 10002

typedef unsigned int uint32;
typedef __attribute__((ext_vector_type(8))) short bf16x8;
typedef __attribute__((ext_vector_type(4))) float f32x4;

// ---------- bf16 helpers ----------
__device__ __forceinline__ float bf2f(unsigned short u){
  union { unsigned int i; float f; } v; v.i = ((unsigned int)u) << 16; return v.f;
}
__device__ __forceinline__ float bflo(unsigned int u){
  union { unsigned int i; float f; } v; v.i = u << 16; return v.f;
}
__device__ __forceinline__ float bfhi(unsigned int u){
  union { unsigned int i; float f; } v; v.i = u & 0xffff0000u; return v.f;
}
__device__ __forceinline__ unsigned short f2bf(float f){
  union { float f; unsigned int i; } v; v.f = f;
  unsigned int i = v.i;
  unsigned int r = (i + 0x7fffu + ((i >> 16) & 1u)) >> 16;  // RNE
  return (unsigned short)r;
}
__device__ __forceinline__ unsigned int packbf(float x, float y){
  return (unsigned int)f2bf(x) | (((unsigned int)f2bf(y)) << 16);
}

// ---------- dtype detection ----------
__global__ void k_detect(const void* __restrict__ emb, int* __restrict__ flag){
  __shared__ int viol;
  if (threadIdx.x == 0) viol = 0;
  __syncthreads();
  const unsigned int* u = (const unsigned int*)emb;
  int my = 0;
  for (int i = threadIdx.x; i < 1024; i += 256){
    unsigned int lo = u[i] & 0xffffu;
    unsigned int ex = (lo >> 7) & 0xffu;
    bool ok = (ex == 0u) || (ex >= 80u && ex <= 127u);
    if (!ok) my++;
  }
  atomicAdd(&viol, my);
  __syncthreads();
  if (threadIdx.x == 0) *flag = (viol < 100) ? 1 : 0;   // 1 = bf16, 0 = fp32
}

// convert float tensor (either packing) to canonical bf16 (big arrays: cemb)
__global__ void k_conv(const void* __restrict__ src, unsigned short* __restrict__ dst,
                       int n, const int* __restrict__ flag){
  int i = blockIdx.x * 256 + threadIdx.x;
  if (i >= n) return;
  if (*flag) dst[i] = ((const unsigned short*)src)[i];
  else       dst[i] = f2bf(((const float*)src)[i]);
}

// fused small-tensor conversion (biases + head weights), one launch
struct Seg { const void* s; unsigned short* d; int n; };
struct Segs9 { Seg v[9]; };
__global__ void k_conv_multi(Segs9 segs, const int* __restrict__ flag, int total){
  int i = blockIdx.x * 256 + threadIdx.x;
  if (i >= total) return;
  int k = 0, idx = i;
  while (idx >= segs.v[k].n){ idx -= segs.v[k].n; k++; }
  unsigned short r;
  if (*flag) r = ((const unsigned short*)segs.v[k].s)[idx];
  else       r = f2bf(((const float*)segs.v[k].s)[idx]);
  segs.v[k].d[idx] = r;
}

// fused convert+transpose for W1(64x128), W2(128x128), Wf(128x128) -> N x K each
__global__ void k_convT3(const void* __restrict__ W1, const void* __restrict__ W2,
                         const void* __restrict__ Wf,
                         unsigned short* __restrict__ o1, unsigned short* __restrict__ o2,
                         unsigned short* __restrict__ o3, const int* __restrict__ flag){
  int i = blockIdx.x * 256 + threadIdx.x;
  if (i >= 8192 + 16384 + 16384) return;
  const void* src; unsigned short* dst; int K, N, idx;
  if (i < 8192){ src = W1; dst = o1; K = 64; N = 128; idx = i; }
  else if (i < 24576){ src = W2; dst = o2; K = 128; N = 128; idx = i - 8192; }
  else { src = Wf; dst = o3; K = 128; N = 128; idx = i - 24576; }
  int k = idx / N, n = idx - k * N;
  unsigned short v;
  if (*flag) v = ((const unsigned short*)src)[idx];
  else       v = f2bf(((const float*)src)[idx]);
  dst[n * K + k] = v;
}

// ---------- counting ----------
__global__ void k_count(const int* __restrict__ idx, int n, uint32* __restrict__ cnt){
  int i = blockIdx.x * 256 + threadIdx.x;
  if (i < n) atomicAdd(&cnt[idx[i]], 1u);
}

__global__ void k_count_sorted(const int* __restrict__ seg, int n, uint32* __restrict__ cnt){
  int base = (blockIdx.x * 256 + threadIdx.x) * 64;
  if (base >= n) return;
  int end = base + 64; if (end > n) end = n;
  int curv = seg[base]; uint32 run = 1;
  for (int i = base + 1; i < end; i++){
    int v = seg[i];
    if (v == curv) run++;
    else { atomicAdd(&cnt[curv], run); curv = v; run = 1; }
  }
  atomicAdd(&cnt[curv], run);
}

// ---------- scans ----------
// big 3-kernel scan (CFG, 400K)
__global__ void k_scan1(const uint32* __restrict__ cnt, int n,
                        uint32* __restrict__ off, uint32* __restrict__ bsums){
  __shared__ uint32 s[256];
  int tid = threadIdx.x;
  int base = blockIdx.x * 1024 + tid * 4;
  uint32 v0 = (base+0<n)?cnt[base+0]:0u, v1 = (base+1<n)?cnt[base+1]:0u;
  uint32 v2 = (base+2<n)?cnt[base+2]:0u, v3 = (base+3<n)?cnt[base+3]:0u;
  uint32 tsum = v0+v1+v2+v3;
  uint32 x = tsum;
  s[tid] = x; __syncthreads();
  for (int o = 1; o < 256; o <<= 1){
    uint32 y = (tid >= o) ? s[tid - o] : 0u;
    __syncthreads();
    x += y; s[tid] = x; __syncthreads();
  }
  uint32 run = x - tsum;
  if (base+0<n) off[base+0]=run; run+=v0;
  if (base+1<n) off[base+1]=run; run+=v1;
  if (base+2<n) off[base+2]=run; run+=v2;
  if (base+3<n) off[base+3]=run;
  if (tid == 255) bsums[blockIdx.x] = x;
}

__global__ void k_scan2(uint32* bsums, int nb){
  __shared__ uint32 s[1024];
  int tid = threadIdx.x;
  uint32 v = (tid < nb) ? bsums[tid] : 0u;
  uint32 x = v;
  s[tid] = x; __syncthreads();
  for (int o = 1; o < 1024; o <<= 1){
    uint32 y = (tid >= o) ? s[tid - o] : 0u;
    __syncthreads();
    x += y; s[tid] = x; __syncthreads();
  }
  if (tid < nb) bsums[tid] = x - v;
}

// scan3 fused with dis computation (CFG)
__global__ void k_scan3_dis(uint32* off, uint32* cur, const uint32* __restrict__ bsums,
                            const uint32* __restrict__ cnt, float* __restrict__ dis, int n){
  int i = blockIdx.x * 256 + threadIdx.x;
  if (i >= n) return;
  uint32 v = off[i] + bsums[i >> 10];
  off[i] = v;
  cur[i] = v;
  dis[i] = rsqrtf((float)cnt[i] + 1.0f);
}

// single-block exclusive scan for small n (<= 1024*PT); optional cur/dis outputs
template<int PT>
__global__ __launch_bounds__(1024)
void k_scan_small(const uint32* __restrict__ cnt, int n, uint32* __restrict__ off,
                  uint32* __restrict__ cur, float* __restrict__ dis){
  __shared__ uint32 tmp[1024];
  int tid = threadIdx.x;
  uint32 local[PT]; uint32 s = 0;
  #pragma unroll
  for (int k = 0; k < PT; k++){
    int idx = tid * PT + k;
    uint32 v = (idx < n) ? cnt[idx] : 0u;
    local[k] = s; s += v;
  }
  uint32 x = s;
  tmp[tid] = x; __syncthreads();
  for (int o = 1; o < 1024; o <<= 1){
    uint32 y = (tid >= o) ? tmp[tid - o] : 0u;
    __syncthreads();
    x += y; tmp[tid] = x; __syncthreads();
  }
  uint32 excl = x - s;
  #pragma unroll
  for (int k = 0; k < PT; k++){
    int idx = tid * PT + k;
    if (idx < n){
      uint32 o2 = excl + local[k];
      off[idx] = o2;
      if (cur) cur[idx] = o2;
      if (dis) dis[idx] = rsqrtf((float)cnt[idx] + 1.0f);
    }
  }
}

// ---------- CSR fill ----------
// windowed: only edges with dest in [lo,hi) -> contiguous L2-resident store region
__global__ void k_fill_win(const int* __restrict__ edges, int E,
                           uint32* __restrict__ cur, int* __restrict__ sorted,
                           int lo, int hi){
  int e = blockIdx.x * 256 + threadIdx.x;
  if (e >= E) return;
  int c = edges[E + e];
  if (c < lo || c >= hi) return;
  int r = edges[e];
  uint32 p = atomicAdd(&cur[c], 1u);
  sorted[p] = r;
}

__global__ void k_fill(const int* __restrict__ edges, int E,
                       uint32* __restrict__ cur, int* __restrict__ sorted){
  int e = blockIdx.x * 256 + threadIdx.x;
  if (e >= E) return;
  int r = edges[e];
  int c = edges[E + e];
  uint32 p = atomicAdd(&cur[c], 1u);
  sorted[p] = r;
}

// ---------- MFMA GEMM: out[r][c] = bf16( dis[r] * sum_k X[r][k]*W[k][c] ), N=128 ----------
template<int K>
__global__ __launch_bounds__(256)
void k_gemm_mfma(const void* __restrict__ Xsrc, const unsigned short* __restrict__ Wt,
                 const float* __restrict__ dis, unsigned short* __restrict__ out,
                 const int* __restrict__ flag, int mixed){
  const int KP = K + 8;
  __shared__ unsigned short Xs[64 * (K + 8)];
  __shared__ unsigned short Ws[128 * (K + 8)];
  int tid = threadIdx.x;
  long row0 = (long)blockIdx.x * 64;

  {
    int n = tid >> 1, half = tid & 1;
    const uint4* src = (const uint4*)(Wt + n * K) + half * (K / 16);
    uint4* dst = (uint4*)(Ws + n * KP) + half * (K / 16);
    #pragma unroll
    for (int i = 0; i < K / 16; i++) dst[i] = src[i];
  }
  {
    int r = tid >> 2, part = tid & 3;
    int isbf = mixed ? *flag : 1;
    uint4* dst = (uint4*)(Xs + r * KP) + part * (K / 32);
    if (isbf){
      const uint4* src = (const uint4*)((const unsigned short*)Xsrc + (row0 + r) * K) + part * (K / 32);
      #pragma unroll
      for (int i = 0; i < K / 32; i++) dst[i] = src[i];
    } else {
      const float4* src = (const float4*)((const float*)Xsrc + (row0 + r) * K) + part * (K / 16);
      #pragma unroll
      for (int i = 0; i < K / 32; i++){
        float4 f0 = src[2*i], f1 = src[2*i+1];
        uint4 u;
        u.x = packbf(f0.x, f0.y); u.y = packbf(f0.z, f0.w);
        u.z = packbf(f1.x, f1.y); u.w = packbf(f1.z, f1.w);
        dst[i] = u;
      }
    }
  }
  __syncthreads();

  int w = tid >> 6, lane = tid & 63, m = lane & 15, q = lane >> 4;
  f32x4 acc[8];
  #pragma unroll
  for (int t = 0; t < 8; t++) acc[t] = (f32x4){0.f, 0.f, 0.f, 0.f};

  const unsigned short* Arow = &Xs[(w * 16 + m) * KP + q * 8];
  const unsigned short* Bbase = &Ws[m * KP + q * 8];
  #pragma unroll
  for (int kc = 0; kc < K; kc += 32){
    bf16x8 a = *(const bf16x8*)(Arow + kc);
    #pragma unroll
    for (int t = 0; t < 8; t++){
      bf16x8 b = *(const bf16x8*)(Bbase + t * 16 * KP + kc);
      acc[t] = __builtin_amdgcn_mfma_f32_16x16x32_bf16(a, b, acc[t], 0, 0, 0);
    }
  }

  float d[4];
  #pragma unroll
  for (int r = 0; r < 4; r++) d[r] = dis[row0 + w * 16 + q * 4 + r];
  #pragma unroll
  for (int t = 0; t < 8; t++){
    #pragma unroll
    for (int r = 0; r < 4; r++){
      long grow = row0 + w * 16 + q * 4 + r;
      out[grow * 128 + t * 16 + m] = f2bf(acc[t][r] * d[r]);
    }
  }
}

// ---------- CSR aggregation: ONE node per wave, 4 edges per iteration ----------
// out[n] = relu( dis[n] * (sum_in hs[r] + hs[n]) + bias )
__global__ __launch_bounds__(256)
void k_agg_wave(const uint4* __restrict__ hs4,
                const uint32* __restrict__ off, const uint32* __restrict__ cnt,
                const int* __restrict__ sorted, const float* __restrict__ dis,
                const uint4* __restrict__ bias4, uint4* __restrict__ out4, int n){
  int gid = blockIdx.x * 256 + threadIdx.x;
  int node = gid >> 6;                 // wave id == node id
  if (node >= n) return;
  int lane = threadIdx.x & 63, grp = lane >> 4, sub = lane & 15;
  uint32 o = off[node], c = cnt[node];
  float a[8] = {0.f,0.f,0.f,0.f,0.f,0.f,0.f,0.f};
  for (uint32 j = grp; j < c; j += 4){
    int r = sorted[o + j];
    uint4 u = hs4[(long)r * 16 + sub];
    a[0] += bflo(u.x); a[1] += bfhi(u.x);
    a[2] += bflo(u.y); a[3] += bfhi(u.y);
    a[4] += bflo(u.z); a[5] += bfhi(u.z);
    a[6] += bflo(u.w); a[7] += bfhi(u.w);
  }
  // reduce across the 4 groups (lanes differing in bits 4,5)
  #pragma unroll
  for (int i = 0; i < 8; i++){
    a[i] += __shfl_xor(a[i], 16);
    a[i] += __shfl_xor(a[i], 32);
  }
  // self-loop (added once, after reduction)
  uint4 su = hs4[(long)node * 16 + sub];
  a[0] += bflo(su.x); a[1] += bfhi(su.x);
  a[2] += bflo(su.y); a[3] += bfhi(su.y);
  a[4] += bflo(su.z); a[5] += bfhi(su.z);
  a[6] += bflo(su.w); a[7] += bfhi(su.w);
  if (grp == 0){
    float d = dis[node];
    uint4 b = bias4[sub];
    float v0 = fmaxf(fmaf(d, a[0], bflo(b.x)), 0.f);
    float v1 = fmaxf(fmaf(d, a[1], bfhi(b.x)), 0.f);
    float v2 = fmaxf(fmaf(d, a[2], bflo(b.y)), 0.f);
    float v3 = fmaxf(fmaf(d, a[3], bfhi(b.y)), 0.f);
    float v4 = fmaxf(fmaf(d, a[4], bflo(b.z)), 0.f);
    float v5 = fmaxf(fmaf(d, a[5], bfhi(b.z)), 0.f);
    float v6 = fmaxf(fmaf(d, a[6], bflo(b.w)), 0.f);
    float v7 = fmaxf(fmaf(d, a[7], bfhi(b.w)), 0.f);
    uint4 ov;
    ov.x = packbf(v0, v1); ov.y = packbf(v2, v3);
    ov.z = packbf(v4, v5); ov.w = packbf(v6, v7);
    out4[(long)node * 16 + sub] = ov;
  }
}

// ---------- per-binary sum, 8 blocks, direct write (no atomics, no pre-zero) ----------
__global__ __launch_bounds__(256)
void k_pool_batch8(const uint4* __restrict__ y4, const uint32* __restrict__ g_cnt,
                   float* __restrict__ g_sum){
  __shared__ float red[16][128];
  int b = blockIdx.x;
  int tid = threadIdx.x;
  int grp = tid >> 4, sub = tid & 15;
  uint32 start = 0;
  for (int i = 0; i < b; i++) start += g_cnt[i];
  uint32 cb = g_cnt[b];
  float a[8] = {0.f,0.f,0.f,0.f,0.f,0.f,0.f,0.f};
  for (uint32 i = grp; i < cb; i += 16){
    uint4 u = y4[(long)(start + i) * 16 + sub];
    a[0] += bflo(u.x); a[1] += bfhi(u.x);
    a[2] += bflo(u.y); a[3] += bfhi(u.y);
    a[4] += bflo(u.z); a[5] += bfhi(u.z);
    a[6] += bflo(u.w); a[7] += bfhi(u.w);
  }
  #pragma unroll
  for (int i = 0; i < 8; i++) red[grp][sub * 8 + i] = a[i];
  __syncthreads();
  if (tid < 128){
    float t = 0.f;
    #pragma unroll
    for (int g = 0; g < 16; g++) t += red[g][tid];
    g_sum[b * 128 + tid] = t;
  }
}

// contiguous segmented mean
__global__ void k_pool_mean(const unsigned int* __restrict__ x2, const uint32* __restrict__ off,
                            const uint32* __restrict__ cnt, unsigned int* __restrict__ pooled2, int nf){
  int f = blockIdx.x; int t = threadIdx.x;
  uint32 o = off[f], c = cnt[f];
  float sx = 0.f, sy = 0.f;
  for (uint32 j = 0; j < c; j++){
    unsigned int u = x2[(long)(o + j) * 64 + t];
    sx += bflo(u); sy += bfhi(u);
  }
  float inv = 1.0f / (float)((c > 0u) ? c : 1u);
  pooled2[(long)f * 64 + t] = packbf(sx * inv, sy * inv);
}

__global__ void k_assemble(const unsigned int* __restrict__ pooled2, const unsigned int* __restrict__ emb2,
                           const int* __restrict__ src, const int* __restrict__ isext,
                           unsigned int* __restrict__ fx2){
  int i = blockIdx.x; int t = threadIdx.x;
  int s = src[i];
  unsigned int v;
  if (isext[i] == 1){
    int idx = s; if (idx < 0) idx = 0; if (idx > VOCAB - 1) idx = VOCAB - 1;
    v = emb2[(long)idx * 64 + t];
  } else {
    int f = s; if (f < 0) f = 0; if (f > N_FUNC - 1) f = N_FUNC - 1;
    v = pooled2[(long)f * 64 + t];
  }
  fx2[(long)i * 64 + t] = v;
}

// ---------- projection head ----------
__global__ __launch_bounds__(256)
void k_head(const float* __restrict__ g_sum, const uint32* __restrict__ g_cnt,
            const unsigned short* __restrict__ Wp1, const unsigned short* __restrict__ bp1,
            const unsigned short* __restrict__ Wp2, const unsigned short* __restrict__ bp2,
            const unsigned short* __restrict__ Wp3, const unsigned short* __restrict__ bp3,
            void* __restrict__ outp, const int* __restrict__ flag){
  __shared__ float G[8 * 128];
  __shared__ float H1[8 * 64];
  __shared__ float H2[8 * 32];
  int tid = threadIdx.x;
  for (int i = tid; i < 1024; i += 256){
    uint32 c = g_cnt[i >> 7];
    G[i] = g_sum[i] / (float)((c > 0u) ? c : 1u);
  }
  __syncthreads();
  for (int i = tid; i < 512; i += 256){
    int b = i >> 6, j = i & 63;
    float a = bf2f(bp1[j]);
    for (int d = 0; d < 128; d++) a = fmaf(G[b * 128 + d], bf2f(Wp1[d * 64 + j]), a);
    H1[i] = fmaxf(a, 0.f);
  }
  __syncthreads();
  {
    int b = tid >> 5, j = tid & 31;
    float a = bf2f(bp2[j]);
    for (int d = 0; d < 64; d++) a = fmaf(H1[b * 64 + d], bf2f(Wp2[d * 32 + j]), a);
    H2[tid] = fmaxf(a, 0.f);
  }
  __syncthreads();
  if (tid < 8){
    float a = bf2f(bp3[0]);
    for (int d = 0; d < 32; d++) a = fmaf(H2[tid * 32 + d], bf2f(Wp3[d]), a);
    float s = 1.f / (1.f + __expf(-a));
    if (*flag) ((unsigned short*)outp)[tid] = f2bf(s);
    else       ((float*)outp)[tid] = s;
  }
}

extern "C" void kernel_launch(void* const* d_in, const int* in_sizes, int n_in,
                              void* d_out, int out_size, void* d_ws, size_t ws_size,
                              hipStream_t stream){
  const void* cfg_x     = d_in[0];
  const int*  cfg_edges = (const int*)d_in[1];
  const int*  node2func = (const int*)d_in[2];
  const int*  fcg_edges = (const int*)d_in[3];
  const int*  fcg_batch = (const int*)d_in[4];
  const int*  fcg_src   = (const int*)d_in[5];
  const int*  fcg_isext = (const int*)d_in[6];
  const void* W1  = d_in[7];
  const void* b1  = d_in[8];
  const void* W2  = d_in[9];
  const void* b2  = d_in[10];
  const void* emb = d_in[11];
  const void* Wf  = d_in[12];
  const void* bfv = d_in[13];
  const void* Wp1 = d_in[14];
  const void* bp1 = d_in[15];
  const void* Wp2 = d_in[16];
  const void* bp2 = d_in[17];
  const void* Wp3 = d_in[18];
  const void* bp3 = d_in[19];

  char* p = (char*)d_ws;
  auto carve = [&](size_t bytes)->char* {
    char* r = p; p += (bytes + 255) & ~(size_t)255; return r;
  };
  unsigned short* A   = (unsigned short*)carve((size_t)N_CFG * 128 * 2);
  unsigned short* Bx  = (unsigned short*)carve((size_t)N_CFG * 128 * 2);
  uint32* cnt_cfg = (uint32*)carve((size_t)N_CFG * 4);
  uint32* off_cfg = (uint32*)carve((size_t)N_CFG * 4);
  uint32* cur_cfg = (uint32*)carve((size_t)N_CFG * 4);
  float*  dis_cfg = (float*) carve((size_t)N_CFG * 4);
  int*    sorted_cfg = (int*)carve((size_t)E_CFG * 4);
  uint32* bsums   = (uint32*)carve(1024 * 4);
  uint32* pool_cnt = (uint32*)carve(N_FUNC * 4);
  uint32* pool_off = (uint32*)carve(N_FUNC * 4);
  unsigned int* pooled2 = (unsigned int*)carve((size_t)N_FUNC * 64 * 4);
  unsigned int* fx2     = (unsigned int*)carve((size_t)N_FCG * 64 * 4);
  unsigned short* hsf   = (unsigned short*)carve((size_t)N_FCG * 128 * 2);
  unsigned short* yf    = (unsigned short*)carve((size_t)N_FCG * 128 * 2);
  uint32* cnt_f = (uint32*)carve(N_FCG * 4);
  uint32* off_f = (uint32*)carve(N_FCG * 4);
  uint32* cur_f = (uint32*)carve(N_FCG * 4);
  float*  dis_f = (float*) carve(N_FCG * 4);
  int*    sorted_f = (int*)carve(E_FCG * 4);
  float*  g_sum = (float*)carve(8 * 128 * 4);
  uint32* g_cnt = (uint32*)carve(8 * 4);
  int*    flag  = (int*)   carve(256);
  unsigned short* cW1t = (unsigned short*)carve(128 * 64 * 2);
  unsigned short* cb1  = (unsigned short*)carve(128 * 2);
  unsigned short* cW2t = (unsigned short*)carve(128 * 128 * 2);
  unsigned short* cb2  = (unsigned short*)carve(128 * 2);
  unsigned short* cemb = (unsigned short*)carve((size_t)VOCAB * 128 * 2);
  unsigned short* cWft = (unsigned short*)carve(128 * 128 * 2);
  unsigned short* cbf  = (unsigned short*)carve(128 * 2);
  unsigned short* cWp1 = (unsigned short*)carve(128 * 64 * 2);
  unsigned short* cbp1 = (unsigned short*)carve(64 * 2);
  unsigned short* cWp2 = (unsigned short*)carve(64 * 32 * 2);
  unsigned short* cbp2 = (unsigned short*)carve(32 * 2);
  unsigned short* cWp3 = (unsigned short*)carve(32 * 2);
  unsigned short* cbp3 = (unsigned short*)carve(2 * 2);

  hipMemsetAsync(cnt_cfg, 0, (size_t)N_CFG * 4, stream);
  hipMemsetAsync(cnt_f,   0, (size_t)N_FCG * 4, stream);
  hipMemsetAsync(pool_cnt,0, (size_t)N_FUNC * 4, stream);
  hipMemsetAsync(g_cnt,   0, 8 * 4, stream);

  // ---- dtype detection + weight canonicalization ----
  k_detect<<<1, 256, 0, stream>>>(emb, flag);
  k_convT3<<<(40960 + 255) / 256, 256, 0, stream>>>(W1, W2, Wf, cW1t, cW2t, cWft, flag);
  {
    Segs9 segs = {{
      { b1,  cb1,  128 }, { b2,  cb2,  128 }, { bfv, cbf,  128 },
      { Wp1, cWp1, 128 * 64 }, { bp1, cbp1, 64 },
      { Wp2, cWp2, 64 * 32 },  { bp2, cbp2, 32 },
      { Wp3, cWp3, 32 },       { bp3, cbp3, 1 }
    }};
    int total = 128 + 128 + 128 + 8192 + 64 + 2048 + 32 + 32 + 1;
    k_conv_multi<<<(total + 255) / 256, 256, 0, stream>>>(segs, flag, total);
  }
  k_conv<<<(VOCAB * 128 + 255) / 256, 256, 0, stream>>>(emb, cemb, VOCAB * 128, flag);

  // ---- CFG graph CSR ----
  k_count<<<(E_CFG + 255) / 256, 256, 0, stream>>>(cfg_edges + E_CFG, E_CFG, cnt_cfg);
  int nb_cfg = (N_CFG + 1023) / 1024;
  k_scan1<<<nb_cfg, 256, 0, stream>>>(cnt_cfg, N_CFG, off_cfg, bsums);
  k_scan2<<<1, 1024, 0, stream>>>(bsums, nb_cfg);
  k_scan3_dis<<<(N_CFG + 255) / 256, 256, 0, stream>>>(off_cfg, cur_cfg, bsums, cnt_cfg, dis_cfg, N_CFG);
  // windowed fill: each pass writes a contiguous ~1.6MB region of sorted_cfg (L2-resident)
  for (int w = 0; w < 4; w++)
    k_fill_win<<<(E_CFG + 255) / 256, 256, 0, stream>>>(cfg_edges, E_CFG, cur_cfg, sorted_cfg,
                                                        w * (N_CFG / 4), (w + 1) * (N_CFG / 4));

  // ---- CFG GCN layer 1 ----
  k_gemm_mfma<64><<<N_CFG / 64, 256, 0, stream>>>(cfg_x, cW1t, dis_cfg, A, flag, 1);
  k_agg_wave<<<N_CFG / 4, 256, 0, stream>>>((const uint4*)A, off_cfg, cnt_cfg, sorted_cfg,
                                            dis_cfg, (const uint4*)cb1, (uint4*)Bx, N_CFG);
  // ---- CFG GCN layer 2 ----
  k_gemm_mfma<128><<<N_CFG / 64, 256, 0, stream>>>(Bx, cW2t, dis_cfg, A, flag, 0);
  k_agg_wave<<<N_CFG / 4, 256, 0, stream>>>((const uint4*)A, off_cfg, cnt_cfg, sorted_cfg,
                                            dis_cfg, (const uint4*)cb2, (uint4*)Bx, N_CFG);

  // ---- per-function mean pool ----
  k_count_sorted<<<((N_CFG + 63) / 64 + 255) / 256, 256, 0, stream>>>(node2func, N_CFG, pool_cnt);
  k_scan_small<8><<<1, 1024, 0, stream>>>(pool_cnt, N_FUNC, pool_off, (uint32*)nullptr, (float*)nullptr);
  k_pool_mean<<<N_FUNC, 64, 0, stream>>>((const unsigned int*)Bx, pool_off, pool_cnt, pooled2, N_FUNC);

  // ---- FCG node features ----
  k_assemble<<<N_FCG, 64, 0, stream>>>(pooled2, (const unsigned int*)cemb, fcg_src, fcg_isext, fx2);

  // ---- FCG graph CSR ----
  k_count<<<(E_FCG + 255) / 256, 256, 0, stream>>>(fcg_edges + E_FCG, E_FCG, cnt_f);
  k_scan_small<10><<<1, 1024, 0, stream>>>(cnt_f, N_FCG, off_f, cur_f, dis_f);
  k_fill<<<(E_FCG + 255) / 256, 256, 0, stream>>>(fcg_edges, E_FCG, cur_f, sorted_f);
  k_count_sorted<<<1, 256, 0, stream>>>(fcg_batch, N_FCG, g_cnt);

  // ---- FCG GCN layer -> y, then per-binary pool ----
  k_gemm_mfma<128><<<N_FCG / 64, 256, 0, stream>>>((const void*)fx2, cWft, dis_f, hsf, flag, 0);
  k_agg_wave<<<N_FCG / 4, 256, 0, stream>>>((const uint4*)hsf, off_f, cnt_f, sorted_f,
                                            dis_f, (const uint4*)cbf, (uint4*)yf, N_FCG);
  k_pool_batch8<<<8, 256, 0, stream>>>((const uint4*)yf, g_cnt, g_sum);

  // ---- head ----
  k_head<<<1, 256, 0, stream>>>(g_sum, g_cnt, cWp1, cbp1, cWp2, cbp2, cWp3, cbp3, d_out, flag);
}

// Round 6
// 773.291 us; speedup vs baseline: 1.1571x; 1.1571x over previous
//
#include <hip/hip_runtime.h>
#include <math.h>

#define N_CFG 400000
#define E_CFG 1600000
#define N_FUNC 8000
#define N_EXT 1600
#define N_FCG (N_FUNC + N_EXT)
#define E_FCG 80000
#define NBATCH 8
#define VOCAB 10002

typedef unsigned int uint32;
typedef __attribute__((ext_vector_type(8))) short bf16x8;
typedef __attribute__((ext_vector_type(4))) float f32x4;

// ---------- bf16 helpers ----------
__device__ __forceinline__ float bf2f(unsigned short u){
  union { unsigned int i; float f; } v; v.i = ((unsigned int)u) << 16; return v.f;
}
__device__ __forceinline__ float bflo(unsigned int u){
  union { unsigned int i; float f; } v; v.i = u << 16; return v.f;
}
__device__ __forceinline__ float bfhi(unsigned int u){
  union { unsigned int i; float f; } v; v.i = u & 0xffff0000u; return v.f;
}
__device__ __forceinline__ unsigned short f2bf(float f){
  union { float f; unsigned int i; } v; v.f = f;
  unsigned int i = v.i;
  unsigned int r = (i + 0x7fffu + ((i >> 16) & 1u)) >> 16;  // RNE
  return (unsigned short)r;
}
__device__ __forceinline__ unsigned int packbf(float x, float y){
  return (unsigned int)f2bf(x) | (((unsigned int)f2bf(y)) << 16);
}

// ---------- dtype detection ----------
__global__ void k_detect(const void* __restrict__ emb, int* __restrict__ flag){
  __shared__ int viol;
  if (threadIdx.x == 0) viol = 0;
  __syncthreads();
  const unsigned int* u = (const unsigned int*)emb;
  int my = 0;
  for (int i = threadIdx.x; i < 1024; i += 256){
    unsigned int lo = u[i] & 0xffffu;
    unsigned int ex = (lo >> 7) & 0xffu;
    bool ok = (ex == 0u) || (ex >= 80u && ex <= 127u);
    if (!ok) my++;
  }
  atomicAdd(&viol, my);
  __syncthreads();
  if (threadIdx.x == 0) *flag = (viol < 100) ? 1 : 0;   // 1 = bf16, 0 = fp32
}

// convert float tensor (either packing) to canonical bf16 (big arrays: cemb)
__global__ void k_conv(const void* __restrict__ src, unsigned short* __restrict__ dst,
                       int n, const int* __restrict__ flag){
  int i = blockIdx.x * 256 + threadIdx.x;
  if (i >= n) return;
  if (*flag) dst[i] = ((const unsigned short*)src)[i];
  else       dst[i] = f2bf(((const float*)src)[i]);
}

// fused small-tensor conversion (biases + head weights), one launch
struct Seg { const void* s; unsigned short* d; int n; };
struct Segs9 { Seg v[9]; };
__global__ void k_conv_multi(Segs9 segs, const int* __restrict__ flag, int total){
  int i = blockIdx.x * 256 + threadIdx.x;
  if (i >= total) return;
  int k = 0, idx = i;
  while (idx >= segs.v[k].n){ idx -= segs.v[k].n; k++; }
  unsigned short r;
  if (*flag) r = ((const unsigned short*)segs.v[k].s)[idx];
  else       r = f2bf(((const float*)segs.v[k].s)[idx]);
  segs.v[k].d[idx] = r;
}

// fused convert+transpose for W1(64x128), W2(128x128), Wf(128x128) -> N x K each
__global__ void k_convT3(const void* __restrict__ W1, const void* __restrict__ W2,
                         const void* __restrict__ Wf,
                         unsigned short* __restrict__ o1, unsigned short* __restrict__ o2,
                         unsigned short* __restrict__ o3, const int* __restrict__ flag){
  int i = blockIdx.x * 256 + threadIdx.x;
  if (i >= 8192 + 16384 + 16384) return;
  const void* src; unsigned short* dst; int K, N, idx;
  if (i < 8192){ src = W1; dst = o1; K = 64; N = 128; idx = i; }
  else if (i < 24576){ src = W2; dst = o2; K = 128; N = 128; idx = i - 8192; }
  else { src = Wf; dst = o3; K = 128; N = 128; idx = i - 24576; }
  int k = idx / N, n = idx - k * N;
  unsigned short v;
  if (*flag) v = ((const unsigned short*)src)[idx];
  else       v = f2bf(((const float*)src)[idx]);
  dst[n * K + k] = v;
}

// ---------- counting ----------
__global__ void k_count(const int* __restrict__ idx, int n, uint32* __restrict__ cnt){
  int i = blockIdx.x * 256 + threadIdx.x;
  if (i < n) atomicAdd(&cnt[idx[i]], 1u);
}

__global__ void k_count_sorted(const int* __restrict__ seg, int n, uint32* __restrict__ cnt){
  int base = (blockIdx.x * 256 + threadIdx.x) * 64;
  if (base >= n) return;
  int end = base + 64; if (end > n) end = n;
  int curv = seg[base]; uint32 run = 1;
  for (int i = base + 1; i < end; i++){
    int v = seg[i];
    if (v == curv) run++;
    else { atomicAdd(&cnt[curv], run); curv = v; run = 1; }
  }
  atomicAdd(&cnt[curv], run);
}

// ---------- scans ----------
__global__ void k_scan1(const uint32* __restrict__ cnt, int n,
                        uint32* __restrict__ off, uint32* __restrict__ bsums){
  __shared__ uint32 s[256];
  int tid = threadIdx.x;
  int base = blockIdx.x * 1024 + tid * 4;
  uint32 v0 = (base+0<n)?cnt[base+0]:0u, v1 = (base+1<n)?cnt[base+1]:0u;
  uint32 v2 = (base+2<n)?cnt[base+2]:0u, v3 = (base+3<n)?cnt[base+3]:0u;
  uint32 tsum = v0+v1+v2+v3;
  uint32 x = tsum;
  s[tid] = x; __syncthreads();
  for (int o = 1; o < 256; o <<= 1){
    uint32 y = (tid >= o) ? s[tid - o] : 0u;
    __syncthreads();
    x += y; s[tid] = x; __syncthreads();
  }
  uint32 run = x - tsum;
  if (base+0<n) off[base+0]=run; run+=v0;
  if (base+1<n) off[base+1]=run; run+=v1;
  if (base+2<n) off[base+2]=run; run+=v2;
  if (base+3<n) off[base+3]=run;
  if (tid == 255) bsums[blockIdx.x] = x;
}

__global__ void k_scan2(uint32* bsums, int nb){
  __shared__ uint32 s[1024];
  int tid = threadIdx.x;
  uint32 v = (tid < nb) ? bsums[tid] : 0u;
  uint32 x = v;
  s[tid] = x; __syncthreads();
  for (int o = 1; o < 1024; o <<= 1){
    uint32 y = (tid >= o) ? s[tid - o] : 0u;
    __syncthreads();
    x += y; s[tid] = x; __syncthreads();
  }
  if (tid < nb) bsums[tid] = x - v;
}

__global__ void k_scan3_dis(uint32* off, uint32* cur, const uint32* __restrict__ bsums,
                            const uint32* __restrict__ cnt, float* __restrict__ dis, int n){
  int i = blockIdx.x * 256 + threadIdx.x;
  if (i >= n) return;
  uint32 v = off[i] + bsums[i >> 10];
  off[i] = v;
  cur[i] = v;
  dis[i] = rsqrtf((float)cnt[i] + 1.0f);
}

template<int PT>
__global__ __launch_bounds__(1024)
void k_scan_small(const uint32* __restrict__ cnt, int n, uint32* __restrict__ off,
                  uint32* __restrict__ cur, float* __restrict__ dis){
  __shared__ uint32 tmp[1024];
  int tid = threadIdx.x;
  uint32 local[PT]; uint32 s = 0;
  #pragma unroll
  for (int k = 0; k < PT; k++){
    int idx = tid * PT + k;
    uint32 v = (idx < n) ? cnt[idx] : 0u;
    local[k] = s; s += v;
  }
  uint32 x = s;
  tmp[tid] = x; __syncthreads();
  for (int o = 1; o < 1024; o <<= 1){
    uint32 y = (tid >= o) ? tmp[tid - o] : 0u;
    __syncthreads();
    x += y; tmp[tid] = x; __syncthreads();
  }
  uint32 excl = x - s;
  #pragma unroll
  for (int k = 0; k < PT; k++){
    int idx = tid * PT + k;
    if (idx < n){
      uint32 o2 = excl + local[k];
      off[idx] = o2;
      if (cur) cur[idx] = o2;
      if (dis) dis[idx] = rsqrtf((float)cnt[idx] + 1.0f);
    }
  }
}

// ---------- CSR fill ----------
// windowed: only edges with dest in [lo,hi) -> contiguous L2-resident store region
__global__ void k_fill_win(const int* __restrict__ edges, int E,
                           uint32* __restrict__ cur, int* __restrict__ sorted,
                           int lo, int hi){
  int e = blockIdx.x * 256 + threadIdx.x;
  if (e >= E) return;
  int c = edges[E + e];
  if (c < lo || c >= hi) return;
  int r = edges[e];
  uint32 p = atomicAdd(&cur[c], 1u);
  sorted[p] = r;
}

__global__ void k_fill(const int* __restrict__ edges, int E,
                       uint32* __restrict__ cur, int* __restrict__ sorted){
  int e = blockIdx.x * 256 + threadIdx.x;
  if (e >= E) return;
  int r = edges[e];
  int c = edges[E + e];
  uint32 p = atomicAdd(&cur[c], 1u);
  sorted[p] = r;
}

// ---------- MFMA GEMM: out[r][c] = bf16( dis[r] * sum_k X[r][k]*W[k][c] ), N=128 ----------
template<int K>
__global__ __launch_bounds__(256)
void k_gemm_mfma(const void* __restrict__ Xsrc, const unsigned short* __restrict__ Wt,
                 const float* __restrict__ dis, unsigned short* __restrict__ out,
                 const int* __restrict__ flag, int mixed){
  const int KP = K + 8;
  __shared__ unsigned short Xs[64 * (K + 8)];
  __shared__ unsigned short Ws[128 * (K + 8)];
  int tid = threadIdx.x;
  long row0 = (long)blockIdx.x * 64;

  {
    int n = tid >> 1, half = tid & 1;
    const uint4* src = (const uint4*)(Wt + n * K) + half * (K / 16);
    uint4* dst = (uint4*)(Ws + n * KP) + half * (K / 16);
    #pragma unroll
    for (int i = 0; i < K / 16; i++) dst[i] = src[i];
  }
  {
    int r = tid >> 2, part = tid & 3;
    int isbf = mixed ? *flag : 1;
    uint4* dst = (uint4*)(Xs + r * KP) + part * (K / 32);
    if (isbf){
      const uint4* src = (const uint4*)((const unsigned short*)Xsrc + (row0 + r) * K) + part * (K / 32);
      #pragma unroll
      for (int i = 0; i < K / 32; i++) dst[i] = src[i];
    } else {
      const float4* src = (const float4*)((const float*)Xsrc + (row0 + r) * K) + part * (K / 16);
      #pragma unroll
      for (int i = 0; i < K / 32; i++){
        float4 f0 = src[2*i], f1 = src[2*i+1];
        uint4 u;
        u.x = packbf(f0.x, f0.y); u.y = packbf(f0.z, f0.w);
        u.z = packbf(f1.x, f1.y); u.w = packbf(f1.z, f1.w);
        dst[i] = u;
      }
    }
  }
  __syncthreads();

  int w = tid >> 6, lane = tid & 63, m = lane & 15, q = lane >> 4;
  f32x4 acc[8];
  #pragma unroll
  for (int t = 0; t < 8; t++) acc[t] = (f32x4){0.f, 0.f, 0.f, 0.f};

  const unsigned short* Arow = &Xs[(w * 16 + m) * KP + q * 8];
  const unsigned short* Bbase = &Ws[m * KP + q * 8];
  #pragma unroll
  for (int kc = 0; kc < K; kc += 32){
    bf16x8 a = *(const bf16x8*)(Arow + kc);
    #pragma unroll
    for (int t = 0; t < 8; t++){
      bf16x8 b = *(const bf16x8*)(Bbase + t * 16 * KP + kc);
      acc[t] = __builtin_amdgcn_mfma_f32_16x16x32_bf16(a, b, acc[t], 0, 0, 0);
    }
  }

  float d[4];
  #pragma unroll
  for (int r = 0; r < 4; r++) d[r] = dis[row0 + w * 16 + q * 4 + r];
  #pragma unroll
  for (int t = 0; t < 8; t++){
    #pragma unroll
    for (int r = 0; r < 4; r++){
      long grow = row0 + w * 16 + q * 4 + r;
      out[grow * 128 + t * 16 + m] = f2bf(acc[t][r] * d[r]);
    }
  }
}

// ---------- CSR aggregation + self-loop + bias + relu (4 nodes/wave, 2-way edge unroll) ----------
// out[n] = relu( dis[n] * (sum_{r in in(n)} hs[r] + hs[n]) + bias )
// [round-5 lesson: 1-node/wave + shuffle variant regressed to 152us, FETCH 277MB — keep this form]
__global__ __launch_bounds__(256)
void k_agg4(const uint4* __restrict__ hs4,
            const uint32* __restrict__ off, const uint32* __restrict__ cnt,
            const int* __restrict__ sorted, const float* __restrict__ dis,
            const uint4* __restrict__ bias4, uint4* __restrict__ out4, int n){
  int tid = threadIdx.x;
  int wave = tid >> 6, lane = tid & 63, grp = lane >> 4, sub = lane & 15;
  int node = blockIdx.x * 16 + wave * 4 + grp;
  if (node >= n) return;
  uint32 o = off[node], c = cnt[node];
  float a[8] = {0.f,0.f,0.f,0.f,0.f,0.f,0.f,0.f};
  uint32 j = 0;
  for (; j + 1 < c; j += 2){
    int r0 = sorted[o + j];
    int r1 = sorted[o + j + 1];
    uint4 u0 = hs4[(long)r0 * 16 + sub];
    uint4 u1 = hs4[(long)r1 * 16 + sub];
    a[0] += bflo(u0.x); a[1] += bfhi(u0.x);
    a[2] += bflo(u0.y); a[3] += bfhi(u0.y);
    a[4] += bflo(u0.z); a[5] += bfhi(u0.z);
    a[6] += bflo(u0.w); a[7] += bfhi(u0.w);
    a[0] += bflo(u1.x); a[1] += bfhi(u1.x);
    a[2] += bflo(u1.y); a[3] += bfhi(u1.y);
    a[4] += bflo(u1.z); a[5] += bfhi(u1.z);
    a[6] += bflo(u1.w); a[7] += bfhi(u1.w);
  }
  if (j < c){
    int r = sorted[o + j];
    uint4 u = hs4[(long)r * 16 + sub];
    a[0] += bflo(u.x); a[1] += bfhi(u.x);
    a[2] += bflo(u.y); a[3] += bfhi(u.y);
    a[4] += bflo(u.z); a[5] += bfhi(u.z);
    a[6] += bflo(u.w); a[7] += bfhi(u.w);
  }
  {
    uint4 u = hs4[(long)node * 16 + sub];
    a[0] += bflo(u.x); a[1] += bfhi(u.x);
    a[2] += bflo(u.y); a[3] += bfhi(u.y);
    a[4] += bflo(u.z); a[5] += bfhi(u.z);
    a[6] += bflo(u.w); a[7] += bfhi(u.w);
  }
  float d = dis[node];
  uint4 b = bias4[sub];
  float v0 = fmaxf(fmaf(d, a[0], bflo(b.x)), 0.f);
  float v1 = fmaxf(fmaf(d, a[1], bfhi(b.x)), 0.f);
  float v2 = fmaxf(fmaf(d, a[2], bflo(b.y)), 0.f);
  float v3 = fmaxf(fmaf(d, a[3], bfhi(b.y)), 0.f);
  float v4 = fmaxf(fmaf(d, a[4], bflo(b.z)), 0.f);
  float v5 = fmaxf(fmaf(d, a[5], bfhi(b.z)), 0.f);
  float v6 = fmaxf(fmaf(d, a[6], bflo(b.w)), 0.f);
  float v7 = fmaxf(fmaf(d, a[7], bfhi(b.w)), 0.f);
  uint4 ov;
  ov.x = packbf(v0, v1); ov.y = packbf(v2, v3);
  ov.z = packbf(v4, v5); ov.w = packbf(v6, v7);
  out4[(long)node * 16 + sub] = ov;
}

// ---------- per-binary sum, 8 blocks, direct write ----------
__global__ __launch_bounds__(256)
void k_pool_batch8(const uint4* __restrict__ y4, const uint32* __restrict__ g_cnt,
                   float* __restrict__ g_sum){
  __shared__ float red[16][128];
  int b = blockIdx.x;
  int tid = threadIdx.x;
  int grp = tid >> 4, sub = tid & 15;
  uint32 start = 0;
  for (int i = 0; i < b; i++) start += g_cnt[i];
  uint32 cb = g_cnt[b];
  float a[8] = {0.f,0.f,0.f,0.f,0.f,0.f,0.f,0.f};
  for (uint32 i = grp; i < cb; i += 16){
    uint4 u = y4[(long)(start + i) * 16 + sub];
    a[0] += bflo(u.x); a[1] += bfhi(u.x);
    a[2] += bflo(u.y); a[3] += bfhi(u.y);
    a[4] += bflo(u.z); a[5] += bfhi(u.z);
    a[6] += bflo(u.w); a[7] += bfhi(u.w);
  }
  #pragma unroll
  for (int i = 0; i < 8; i++) red[grp][sub * 8 + i] = a[i];
  __syncthreads();
  if (tid < 128){
    float t = 0.f;
    #pragma unroll
    for (int g = 0; g < 16; g++) t += red[g][tid];
    g_sum[b * 128 + tid] = t;
  }
}

// contiguous segmented mean
__global__ void k_pool_mean(const unsigned int* __restrict__ x2, const uint32* __restrict__ off,
                            const uint32* __restrict__ cnt, unsigned int* __restrict__ pooled2, int nf){
  int f = blockIdx.x; int t = threadIdx.x;
  uint32 o = off[f], c = cnt[f];
  float sx = 0.f, sy = 0.f;
  for (uint32 j = 0; j < c; j++){
    unsigned int u = x2[(long)(o + j) * 64 + t];
    sx += bflo(u); sy += bfhi(u);
  }
  float inv = 1.0f / (float)((c > 0u) ? c : 1u);
  pooled2[(long)f * 64 + t] = packbf(sx * inv, sy * inv);
}

__global__ void k_assemble(const unsigned int* __restrict__ pooled2, const unsigned int* __restrict__ emb2,
                           const int* __restrict__ src, const int* __restrict__ isext,
                           unsigned int* __restrict__ fx2){
  int i = blockIdx.x; int t = threadIdx.x;
  int s = src[i];
  unsigned int v;
  if (isext[i] == 1){
    int idx = s; if (idx < 0) idx = 0; if (idx > VOCAB - 1) idx = VOCAB - 1;
    v = emb2[(long)idx * 64 + t];
  } else {
    int f = s; if (f < 0) f = 0; if (f > N_FUNC - 1) f = N_FUNC - 1;
    v = pooled2[(long)f * 64 + t];
  }
  fx2[(long)i * 64 + t] = v;
}

// ---------- projection head ----------
__global__ __launch_bounds__(256)
void k_head(const float* __restrict__ g_sum, const uint32* __restrict__ g_cnt,
            const unsigned short* __restrict__ Wp1, const unsigned short* __restrict__ bp1,
            const unsigned short* __restrict__ Wp2, const unsigned short* __restrict__ bp2,
            const unsigned short* __restrict__ Wp3, const unsigned short* __restrict__ bp3,
            void* __restrict__ outp, const int* __restrict__ flag){
  __shared__ float G[8 * 128];
  __shared__ float H1[8 * 64];
  __shared__ float H2[8 * 32];
  int tid = threadIdx.x;
  for (int i = tid; i < 1024; i += 256){
    uint32 c = g_cnt[i >> 7];
    G[i] = g_sum[i] / (float)((c > 0u) ? c : 1u);
  }
  __syncthreads();
  for (int i = tid; i < 512; i += 256){
    int b = i >> 6, j = i & 63;
    float a = bf2f(bp1[j]);
    for (int d = 0; d < 128; d++) a = fmaf(G[b * 128 + d], bf2f(Wp1[d * 64 + j]), a);
    H1[i] = fmaxf(a, 0.f);
  }
  __syncthreads();
  {
    int b = tid >> 5, j = tid & 31;
    float a = bf2f(bp2[j]);
    for (int d = 0; d < 64; d++) a = fmaf(H1[b * 64 + d], bf2f(Wp2[d * 32 + j]), a);
    H2[tid] = fmaxf(a, 0.f);
  }
  __syncthreads();
  if (tid < 8){
    float a = bf2f(bp3[0]);
    for (int d = 0; d < 32; d++) a = fmaf(H2[tid * 32 + d], bf2f(Wp3[d]), a);
    float s = 1.f / (1.f + __expf(-a));
    if (*flag) ((unsigned short*)outp)[tid] = f2bf(s);
    else       ((float*)outp)[tid] = s;
  }
}

extern "C" void kernel_launch(void* const* d_in, const int* in_sizes, int n_in,
                              void* d_out, int out_size, void* d_ws, size_t ws_size,
                              hipStream_t stream){
  const void* cfg_x     = d_in[0];
  const int*  cfg_edges = (const int*)d_in[1];
  const int*  node2func = (const int*)d_in[2];
  const int*  fcg_edges = (const int*)d_in[3];
  const int*  fcg_batch = (const int*)d_in[4];
  const int*  fcg_src   = (const int*)d_in[5];
  const int*  fcg_isext = (const int*)d_in[6];
  const void* W1  = d_in[7];
  const void* b1  = d_in[8];
  const void* W2  = d_in[9];
  const void* b2  = d_in[10];
  const void* emb = d_in[11];
  const void* Wf  = d_in[12];
  const void* bfv = d_in[13];
  const void* Wp1 = d_in[14];
  const void* bp1 = d_in[15];
  const void* Wp2 = d_in[16];
  const void* bp2 = d_in[17];
  const void* Wp3 = d_in[18];
  const void* bp3 = d_in[19];

  char* p = (char*)d_ws;
  auto carve = [&](size_t bytes)->char* {
    char* r = p; p += (bytes + 255) & ~(size_t)255; return r;
  };
  unsigned short* A   = (unsigned short*)carve((size_t)N_CFG * 128 * 2);
  unsigned short* Bx  = (unsigned short*)carve((size_t)N_CFG * 128 * 2);
  uint32* cnt_cfg = (uint32*)carve((size_t)N_CFG * 4);
  uint32* off_cfg = (uint32*)carve((size_t)N_CFG * 4);
  uint32* cur_cfg = (uint32*)carve((size_t)N_CFG * 4);
  float*  dis_cfg = (float*) carve((size_t)N_CFG * 4);
  int*    sorted_cfg = (int*)carve((size_t)E_CFG * 4);
  uint32* bsums   = (uint32*)carve(1024 * 4);
  uint32* pool_cnt = (uint32*)carve(N_FUNC * 4);
  uint32* pool_off = (uint32*)carve(N_FUNC * 4);
  unsigned int* pooled2 = (unsigned int*)carve((size_t)N_FUNC * 64 * 4);
  unsigned int* fx2     = (unsigned int*)carve((size_t)N_FCG * 64 * 4);
  unsigned short* hsf   = (unsigned short*)carve((size_t)N_FCG * 128 * 2);
  unsigned short* yf    = (unsigned short*)carve((size_t)N_FCG * 128 * 2);
  uint32* cnt_f = (uint32*)carve(N_FCG * 4);
  uint32* off_f = (uint32*)carve(N_FCG * 4);
  uint32* cur_f = (uint32*)carve(N_FCG * 4);
  float*  dis_f = (float*) carve(N_FCG * 4);
  int*    sorted_f = (int*)carve(E_FCG * 4);
  float*  g_sum = (float*)carve(8 * 128 * 4);
  uint32* g_cnt = (uint32*)carve(8 * 4);
  int*    flag  = (int*)   carve(256);
  unsigned short* cW1t = (unsigned short*)carve(128 * 64 * 2);
  unsigned short* cb1  = (unsigned short*)carve(128 * 2);
  unsigned short* cW2t = (unsigned short*)carve(128 * 128 * 2);
  unsigned short* cb2  = (unsigned short*)carve(128 * 2);
  unsigned short* cemb = (unsigned short*)carve((size_t)VOCAB * 128 * 2);
  unsigned short* cWft = (unsigned short*)carve(128 * 128 * 2);
  unsigned short* cbf  = (unsigned short*)carve(128 * 2);
  unsigned short* cWp1 = (unsigned short*)carve(128 * 64 * 2);
  unsigned short* cbp1 = (unsigned short*)carve(64 * 2);
  unsigned short* cWp2 = (unsigned short*)carve(64 * 32 * 2);
  unsigned short* cbp2 = (unsigned short*)carve(32 * 2);
  unsigned short* cWp3 = (unsigned short*)carve(32 * 2);
  unsigned short* cbp3 = (unsigned short*)carve(2 * 2);

  hipMemsetAsync(cnt_cfg, 0, (size_t)N_CFG * 4, stream);
  hipMemsetAsync(cnt_f,   0, (size_t)N_FCG * 4, stream);
  hipMemsetAsync(pool_cnt,0, (size_t)N_FUNC * 4, stream);
  hipMemsetAsync(g_cnt,   0, 8 * 4, stream);

  // ---- dtype detection + weight canonicalization ----
  k_detect<<<1, 256, 0, stream>>>(emb, flag);
  k_convT3<<<(40960 + 255) / 256, 256, 0, stream>>>(W1, W2, Wf, cW1t, cW2t, cWft, flag);
  {
    Segs9 segs = {{
      { b1,  cb1,  128 }, { b2,  cb2,  128 }, { bfv, cbf,  128 },
      { Wp1, cWp1, 128 * 64 }, { bp1, cbp1, 64 },
      { Wp2, cWp2, 64 * 32 },  { bp2, cbp2, 32 },
      { Wp3, cWp3, 32 },       { bp3, cbp3, 1 }
    }};
    int total = 128 + 128 + 128 + 8192 + 64 + 2048 + 32 + 32 + 1;
    k_conv_multi<<<(total + 255) / 256, 256, 0, stream>>>(segs, flag, total);
  }
  k_conv<<<(VOCAB * 128 + 255) / 256, 256, 0, stream>>>(emb, cemb, VOCAB * 128, flag);

  // ---- CFG graph CSR ----
  k_count<<<(E_CFG + 255) / 256, 256, 0, stream>>>(cfg_edges + E_CFG, E_CFG, cnt_cfg);
  int nb_cfg = (N_CFG + 1023) / 1024;
  k_scan1<<<nb_cfg, 256, 0, stream>>>(cnt_cfg, N_CFG, off_cfg, bsums);
  k_scan2<<<1, 1024, 0, stream>>>(bsums, nb_cfg);
  k_scan3_dis<<<(N_CFG + 255) / 256, 256, 0, stream>>>(off_cfg, cur_cfg, bsums, cnt_cfg, dis_cfg, N_CFG);
  // windowed fill: each pass writes a contiguous ~1.6MB region of sorted_cfg (L2-resident)
  for (int w = 0; w < 4; w++)
    k_fill_win<<<(E_CFG + 255) / 256, 256, 0, stream>>>(cfg_edges, E_CFG, cur_cfg, sorted_cfg,
                                                        w * (N_CFG / 4), (w + 1) * (N_CFG / 4));

  // ---- CFG GCN layer 1 ----
  k_gemm_mfma<64><<<N_CFG / 64, 256, 0, stream>>>(cfg_x, cW1t, dis_cfg, A, flag, 1);
  k_agg4<<<N_CFG / 16, 256, 0, stream>>>((const uint4*)A, off_cfg, cnt_cfg, sorted_cfg,
                                         dis_cfg, (const uint4*)cb1, (uint4*)Bx, N_CFG);
  // ---- CFG GCN layer 2 ----
  k_gemm_mfma<128><<<N_CFG / 64, 256, 0, stream>>>(Bx, cW2t, dis_cfg, A, flag, 0);
  k_agg4<<<N_CFG / 16, 256, 0, stream>>>((const uint4*)A, off_cfg, cnt_cfg, sorted_cfg,
                                         dis_cfg, (const uint4*)cb2, (uint4*)Bx, N_CFG);

  // ---- per-function mean pool ----
  k_count_sorted<<<((N_CFG + 63) / 64 + 255) / 256, 256, 0, stream>>>(node2func, N_CFG, pool_cnt);
  k_scan_small<8><<<1, 1024, 0, stream>>>(pool_cnt, N_FUNC, pool_off, (uint32*)nullptr, (float*)nullptr);
  k_pool_mean<<<N_FUNC, 64, 0, stream>>>((const unsigned int*)Bx, pool_off, pool_cnt, pooled2, N_FUNC);

  // ---- FCG node features ----
  k_assemble<<<N_FCG, 64, 0, stream>>>(pooled2, (const unsigned int*)cemb, fcg_src, fcg_isext, fx2);

  // ---- FCG graph CSR ----
  k_count<<<(E_FCG + 255) / 256, 256, 0, stream>>>(fcg_edges + E_FCG, E_FCG, cnt_f);
  k_scan_small<10><<<1, 1024, 0, stream>>>(cnt_f, N_FCG, off_f, cur_f, dis_f);
  k_fill<<<(E_FCG + 255) / 256, 256, 0, stream>>>(fcg_edges, E_FCG, cur_f, sorted_f);
  k_count_sorted<<<1, 256, 0, stream>>>(fcg_batch, N_FCG, g_cnt);

  // ---- FCG GCN layer -> y, then per-binary pool ----
  k_gemm_mfma<128><<<N_FCG / 64, 256, 0, stream>>>((const void*)fx2, cWft, dis_f, hsf, flag, 0);
  k_agg4<<<N_FCG / 16, 256, 0, stream>>>((const uint4*)hsf, off_f, cnt_f, sorted_f,
                                         dis_f, (const uint4*)cbf, (uint4*)yf, N_FCG);
  k_pool_batch8<<<8, 256, 0, stream>>>((const uint4*)yf, g_cnt, g_sum);

  // ---- head ----
  k_head<<<1, 256, 0, stream>>>(g_sum, g_cnt, cWp1, cbp1, cWp2, cbp2, cWp3, cbp3, d_out, flag);
}